// Round 10
// baseline (171.275 us; speedup 1.0000x reference)
//
#include <hip/hip_runtime.h>
#include <hip/hip_fp16.h>

typedef _Float16 half8 __attribute__((ext_vector_type(8)));
typedef _Float16 half4v __attribute__((ext_vector_type(4)));
typedef float f32x4 __attribute__((ext_vector_type(4)));

#define NSEQ 2048
#define DMOD 1024
#define NHEAD 16
#define DK 64

// async global->LDS, 16B per lane; LDS dest = wave-uniform base + lane*16
#define GLOAD_LDS16(gp, lp) __builtin_amdgcn_global_load_lds(                 \
    (const __attribute__((address_space(1))) void*)(gp),                      \
    (__attribute__((address_space(3))) void*)(lp), 16, 0, 0)

// s_waitcnt imm (gfx9): vmcnt[3:0]=bits[3:0], expcnt=bits[6:4], lgkm=bits[11:8]
#define WAIT_VM(n) (0xF70 | (n))

// ---------------------------------------------------------------------------
// PACKED tile layout for GEMM operands (K=1024):
//   PACK[((st*32 + kc)*64 + ln)*8 + j] = M[st*16 + (ln&15)][kc*32 + (ln>>4)*8 + j]
// One global_load_lds per wave = contiguous 1 KiB burst in fragment order.
// ---------------------------------------------------------------------------

// cast fp32 -> fp16 AND pack into tile order: x (2M) | Wq|Wk|Wv|Wo (1M each).
// Extended (when ws allows): w in [12288,20480) converts distance_bias
// fp32 -> fp16 flat (512 floats per wave-unit), removing the cvt_bias
// dispatch (small streaming kernels pay a ~10us launch/ramp floor).
__global__ __launch_bounds__(256) void cast_pack(
    const float* __restrict__ x, const float* __restrict__ wq,
    const float* __restrict__ wk, const float* __restrict__ wv,
    const float* __restrict__ wo, const float* __restrict__ db,
    _Float16* __restrict__ dst, _Float16* __restrict__ bh)
{
    const int w = blockIdx.x * 4 + (threadIdx.x >> 6);
    const int ln = threadIdx.x & 63, m = ln & 15, qd = ln >> 4;
    if (w >= 12288) {   // bias conversion chunk (flat copy, no repack)
        const int loc = w - 12288;                  // [0, 8192)
        const float* p = db + (size_t)loc * 512 + ln * 8;
        float4 a = *(const float4*)p, b = *(const float4*)(p + 4);
        half8 h;
        h[0] = (_Float16)a.x; h[1] = (_Float16)a.y; h[2] = (_Float16)a.z; h[3] = (_Float16)a.w;
        h[4] = (_Float16)b.x; h[5] = (_Float16)b.y; h[6] = (_Float16)b.z; h[7] = (_Float16)b.w;
        *(half8*)(bh + (size_t)loc * 512 + ln * 8) = h;
        return;
    }
    const float* src; _Float16* d; int loc;
    if (w < 4096) { src = x; d = dst; loc = w; }                // x: 128 st x 32 kc
    else {
        const int w2 = w - 4096, mat = w2 >> 11;                 // W: 64 st x 32 kc
        loc = w2 & 2047;
        src = mat == 0 ? wq : mat == 1 ? wk : mat == 2 ? wv : wo;
        d = dst + 2097152 + mat * 1048576;
    }
    const int st = loc >> 5, kc = loc & 31;
    const float* p = src + (size_t)(st * 16 + m) * 1024 + kc * 32 + qd * 8;
    float4 a = *(const float4*)p, b = *(const float4*)(p + 4);
    half8 h;
    h[0] = (_Float16)a.x; h[1] = (_Float16)a.y; h[2] = (_Float16)a.z; h[3] = (_Float16)a.w;
    h[4] = (_Float16)b.x; h[5] = (_Float16)b.y; h[6] = (_Float16)b.z; h[7] = (_Float16)b.w;
    *(half8*)(d + (size_t)(loc * 64 + ln) * 8) = h;
}

// fallback bias fp32 -> fp16 (only if ws too small for the fused path)
__global__ __launch_bounds__(256) void cvt_bias(
    const float* __restrict__ src, _Float16* __restrict__ dst)
{
    int i = (blockIdx.x * 256 + threadIdx.x) * 4;
    float4 v = *(const float4*)(src + i);
    half4v h;
    h[0] = (_Float16)v.x; h[1] = (_Float16)v.y;
    h[2] = (_Float16)v.z; h[3] = (_Float16)v.w;
    *(half4v*)(dst + i) = h;
}

// ---------------------------------------------------------------------------
// Tiled GEMM, generalized K-step (BK), DOUBLE-buffered, staged ONE STEP
// AHEAD with counted vmcnt + 2 raw barriers per step.  BK=64 halves the
// sync-rendezvous count vs BK=32 (proven r9: -11 us).  PACKED operands.
// C = A @ W^T + bias, K = 1024.  Wave grid 2x2.
// MODE 0: fused QKV epilogue (Q pre-scaled 0.125 at [h][n][dk]; K,V in attn
//         frag-tile order KIDX/VIDX).  Now BM=128 (128x128 tiles): W-panel
//         re-reads drop 32->16 (-33% L2/L3 traffic, 288->192 MB) and the
//         64x64 wave tile doubles MFMA-per-ds_read intensity (2.0 vs 1.33).
// MODE 1: fp32 out (final projection), A = A1 + A2 summed via native fp16
//         vector add (v_pk_add_f16 - numerically identical to the fp32
//         add+round path, 1/8 the VALU ops).
// ---------------------------------------------------------------------------
template<int BM, int BN, int BK, int MODE>
__global__ __launch_bounds__(256) void tgemm(
    const _Float16* __restrict__ A, const _Float16* __restrict__ A2,
    const _Float16* __restrict__ W0, const _Float16* __restrict__ W1,
    const _Float16* __restrict__ W2,
    const float* __restrict__ b0, const float* __restrict__ b1,
    const float* __restrict__ b2,
    _Float16* __restrict__ oQ, _Float16* __restrict__ oK,
    _Float16* __restrict__ oV, float* __restrict__ oF)
{
    constexpr int MT = BM / 32, NT = BN / 32;
    constexpr int KC = BK / 32;                  // 32-col K-chunks per step
    constexpr int NSTEP = 1024 / BK;
    constexpr int NAc = BM / 64, NBc = BN / 64;  // DMA instr/wave per chunk
    constexpr int SDMA = KC * ((MODE == 1 ? 2 * NAc : NAc) + NBc);
    __shared__ _Float16 sA[2 * BM * BK];
    __shared__ _Float16 sA2[MODE == 1 ? 2 * BM * BK : 1];
    __shared__ _Float16 sB[2 * BN * BK];
    const int tid = threadIdx.x, wv = tid >> 6, ln = tid & 63;
    const int m = ln & 15, qd = ln >> 4;
    const int row0 = blockIdx.x * BM;

    int sel = 0, colbase;
    const _Float16* W; const float* bias;
    if constexpr (MODE == 0) {
        sel = blockIdx.y >> 3;
        colbase = (blockIdx.y & 7) * BN;
        W = sel == 0 ? W0 : sel == 1 ? W1 : W2;
        bias = sel == 0 ? b0 : sel == 1 ? b1 : b2;
    } else {
        colbase = blockIdx.y * BN;
        W = W0; bias = b0;
    }
    const int wr = wv >> 1, wc = wv & 1;

    f32x4 acc[MT][NT];
#pragma unroll
    for (int i = 0; i < MT; ++i)
#pragma unroll
        for (int j = 0; j < NT; ++j) acc[i][j] = (f32x4){0.f, 0.f, 0.f, 0.f};

    auto stage = [&](int s, int b) {
        _Float16* dA = sA + b * (BM * BK);
        _Float16* dB = sB + b * (BN * BK);
#pragma unroll
        for (int c = 0; c < KC; ++c) {
            const int kc = s * KC + c;
#pragma unroll
            for (int ra = 0; ra < NAc; ++ra) {
                const int st = ra * 4 + wv;
                GLOAD_LDS16(A + ((size_t)((row0 >> 4) + st) * 32 + kc) * 512 + ln * 8,
                            dA + (c * (BM / 16) + st) * 512);
                if constexpr (MODE == 1) {
                    _Float16* dA2 = sA2 + b * (BM * BK);
                    GLOAD_LDS16(A2 + ((size_t)((row0 >> 4) + st) * 32 + kc) * 512 + ln * 8,
                                dA2 + (c * (BM / 16) + st) * 512);
                }
            }
#pragma unroll
            for (int rb = 0; rb < NBc; ++rb) {
                const int st = rb * 4 + wv;
                GLOAD_LDS16(W + ((size_t)((colbase >> 4) + st) * 32 + kc) * 512 + ln * 8,
                            dB + (c * (BN / 16) + st) * 512);
            }
        }
    };
    auto step = [&](int b) {
#pragma unroll
        for (int c = 0; c < KC; ++c) {
            const _Float16* cA = sA + b * (BM * BK) + c * (BM * 32);
            const _Float16* cB = sB + b * (BN * BK) + c * (BN * 32);
            half8 af[MT], bf[NT];
#pragma unroll
            for (int i = 0; i < MT; ++i) {
                const int off = ((wr * MT + i) * 64 + ln) * 8;
                if constexpr (MODE == 1) {
                    const _Float16* cA2 = sA2 + b * (BM * BK) + c * (BM * 32);
                    half8 xv = *(const half8*)(cA + off);
                    half8 yv = *(const half8*)(cA2 + off);
                    af[i] = xv + yv;   // v_pk_add_f16: == fp32-add-then-round
                } else {
                    af[i] = *(const half8*)(cA + off);
                }
            }
#pragma unroll
            for (int j = 0; j < NT; ++j)
                bf[j] = *(const half8*)(cB + ((wc * NT + j) * 64 + ln) * 8);
#pragma unroll
            for (int i = 0; i < MT; ++i)
#pragma unroll
                for (int j = 0; j < NT; ++j)
                    acc[i][j] = __builtin_amdgcn_mfma_f32_16x16x32_f16(af[i], bf[j], acc[i][j], 0, 0, 0);
        }
    };

    // K-loop: dbuf, stage 1 step ahead, counted vmcnt, 2 barriers/step.
    stage(0, 0);
#pragma unroll
    for (int s = 0; s < NSTEP; ++s) {
        if (s) __builtin_amdgcn_s_barrier();          // prev step's reads done
        if (s + 1 < NSTEP) {
            stage(s + 1, (s + 1) & 1);
            __builtin_amdgcn_s_waitcnt(WAIT_VM(SDMA));  // step s's loads done
        } else {
            __builtin_amdgcn_s_waitcnt(WAIT_VM(0));     // final: drain all
        }
        __builtin_amdgcn_s_barrier();                 // buf[s&1] visible
        step(s & 1);
    }

#pragma unroll
    for (int j = 0; j < NT; ++j) {
        const int col = colbase + wc * (BN / 2) + j * 16 + m;
        const float bv = bias[col];
#pragma unroll
        for (int i = 0; i < MT; ++i) {
            const int crow0 = row0 + wr * (BM / 2) + i * 16 + qd * 4;
            if constexpr (MODE == 1) {
#pragma unroll
                for (int r = 0; r < 4; ++r)
                    oF[(size_t)(crow0 + r) * DMOD + col] = acc[i][j][r] + bv;
            } else {
                const int h = col >> 6, d = col & 63;
                if (sel == 0) {
#pragma unroll
                    for (int r = 0; r < 4; ++r)
                        oQ[h * (NSEQ * DK) + (crow0 + r) * DK + d] =
                            (_Float16)((acc[i][j][r] + bv) * 0.125f);
                } else if (sel == 1) {
                    // K frag-tile order (KIDX)
#pragma unroll
                    for (int r = 0; r < 4; ++r) {
                        const int n = crow0 + r;
                        oK[(size_t)(((h * 16 + (n >> 7)) * 16
                                     + ((n >> 4) & 7) * 2 + (d >> 5)) * 64
                                    + (n & 15) + 16 * ((d >> 3) & 3)) * 8
                           + (d & 7)] = (_Float16)(acc[i][j][r] + bv);
                    }
                } else {
                    // V frag-tile order (VIDX); 4 consecutive n contiguous
                    half4v hv;
#pragma unroll
                    for (int r = 0; r < 4; ++r) hv[r] = (_Float16)(acc[i][j][r] + bv);
                    const int n0 = crow0;
                    *(half4v*)(oV + (size_t)(((h * 16 + (n0 >> 7)) * 16
                                              + ((n0 >> 5) & 3) * 4 + ((d >> 4) & 3)) * 64
                                             + (d & 15) + 16 * ((n0 >> 3) & 3)) * 8
                               + (n0 & 7)) = hv;
                }
            }
        }
    }
}

// ---------------------------------------------------------------------------
// Attention v12-exact (proven 47.6 us: 8 waves x 16 q, sP round-trip,
// KVBLK=128, 2 __syncthreads per step, fp16 bias).  UNTOUCHED.
// LDS = 16(K) + 16(V) + 32(P) = 64 KB -> 2 blocks/CU, 16 waves/CU.
// ---------------------------------------------------------------------------
__global__ __launch_bounds__(512, 4) void attn(
    const _Float16* __restrict__ Q, const _Float16* __restrict__ Kt,
    const _Float16* __restrict__ Vt, const _Float16* __restrict__ bias_h,
    _Float16* __restrict__ Op)
{
    __shared__ _Float16 sK[8192];
    __shared__ _Float16 sV[8192];
    __shared__ _Float16 sP[16384];  // [8 waves][2048]
    const int tid = threadIdx.x, wv = tid >> 6, ln = tid & 63;
    const int m = ln & 15, qd = ln >> 4;
    const int h = blockIdx.x;
    const int q0 = blockIdx.y * 128 + wv * 16;    // this wave's 16 q-rows
    const int kvb = blockIdx.z * 8;               // first 128-key step of half
    const _Float16* Qh = Q + h * (NSEQ * DK);
    const _Float16* Kh = Kt + h * (NSEQ * DK) + kvb * 8192;  // [step][f][ln][8]
    const _Float16* Vh = Vt + h * (NSEQ * DK) + kvb * 8192;
    const _Float16* brow = bias_h + (size_t)(q0 + m) * NSEQ + kvb * 128;

    // Q B-fragments (pre-scaled by 1/8), 2 dk-halves
    half8 qf[2];
    qf[0] = *(const half8*)(Qh + (q0 + m) * DK + qd * 8);
    qf[1] = *(const half8*)(Qh + (q0 + m) * DK + 32 + qd * 8);

    f32x4 oacc[4], oU[4];
#pragma unroll
    for (int v = 0; v < 4; ++v) {
        oacc[v] = (f32x4){0.f, 0.f, 0.f, 0.f};
        oU[v]   = (f32x4){0.f, 0.f, 0.f, 0.f};
    }
    float bsum = 0.f;

    for (int ls = 0; ls < 8; ++ls) {
        if (ls) __syncthreads();   // previous step's LDS reads complete
        // --- stage K,V: 16 frags each, 2 per wave ---
        GLOAD_LDS16(Kh + ls * 8192 + wv * 512 + ln * 8, sK + wv * 512);
        GLOAD_LDS16(Kh + ls * 8192 + (wv + 8) * 512 + ln * 8, sK + (wv + 8) * 512);
        GLOAD_LDS16(Vh + ls * 8192 + wv * 512 + ln * 8, sV + wv * 512);
        GLOAD_LDS16(Vh + ls * 8192 + (wv + 8) * 512 + ln * 8, sV + (wv + 8) * 512);
        // --- bias regs (fp16, 8B/lane); drain together with DMA ---
        half4v bcur[8];
#pragma unroll
        for (int t = 0; t < 8; ++t)
            bcur[t] = *(const half4v*)(brow + ls * 128 + t * 16 + qd * 4);
        __syncthreads();           // staging visible

        // --- S^T phase ---
#pragma unroll
        for (int t = 0; t < 8; ++t) {
            half8 kf0 = *(const half8*)(sK + ((t * 2 + 0) * 64 + ln) * 8);
            half8 kf1 = *(const half8*)(sK + ((t * 2 + 1) * 64 + ln) * 8);
            f32x4 s = {0.f, 0.f, 0.f, 0.f};
            s = __builtin_amdgcn_mfma_f32_16x16x32_f16(kf0, qf[0], s, 0, 0, 0);
            s = __builtin_amdgcn_mfma_f32_16x16x32_f16(kf1, qf[1], s, 0, 0, 0);
            float p0 = __expf(s[0] - (float)bcur[t][0]);
            float p1 = __expf(s[1] - (float)bcur[t][1]);
            float p2 = __expf(s[2] - (float)bcur[t][2]);
            float p3 = __expf(s[3] - (float)bcur[t][3]);
            bsum += (p0 + p1) + (p2 + p3);
            half4v ph;
            ph[0] = (_Float16)p0; ph[1] = (_Float16)p1;
            ph[2] = (_Float16)p2; ph[3] = (_Float16)p3;
            // (q=m, key=t*16+qd*4+r) -> A-frag slot (verified transform)
            *(half4v*)(sP + wv * 2048 + (t >> 1) * 512
                       + (((t & 1) * 2 + (qd >> 1)) * 16 + m) * 8
                       + (qd & 1) * 4) = ph;
        }

        // --- PV phase ---
#pragma unroll
        for (int kk = 0; kk < 4; ++kk) {
            half8 pa = *(const half8*)(sP + wv * 2048 + kk * 512 + ln * 8);
#pragma unroll
            for (int vt = 0; vt < 4; ++vt) {
                half8 vb = *(const half8*)(sV + ((kk * 4 + vt) * 64 + ln) * 8);
                oU[vt] = __builtin_amdgcn_mfma_f32_16x16x32_f16(pa, vb, oU[vt], 0, 0, 0);
            }
        }

        // --- end of a 256-key softmax block: fold in 1/(8*sum) ---
        if (ls & 1) {
            float s2 = bsum;
            s2 += __shfl_xor(s2, 16, 64);
            s2 += __shfl_xor(s2, 32, 64);
            float inv = 1.0f / (8.0f * s2);
            float iv[4];
#pragma unroll
            for (int r = 0; r < 4; ++r) iv[r] = __shfl(inv, qd * 4 + r, 64);
#pragma unroll
            for (int vt = 0; vt < 4; ++vt) {
#pragma unroll
                for (int r = 0; r < 4; ++r) oacc[vt][r] += iv[r] * oU[vt][r];
                oU[vt] = (f32x4){0.f, 0.f, 0.f, 0.f};
            }
            bsum = 0.f;
        }
    }

    // ---- store partial O in PACK layout (out-proj A-operand) ----
    // n = q0 + qd*4 + r ; d = h*64 + vt*16 + m
    _Float16* Opz = Op + (size_t)blockIdx.z * 2097152;
    const int st = blockIdx.y * 8 + wv;
#pragma unroll
    for (int vt = 0; vt < 4; ++vt) {
        const int d = h * 64 + vt * 16 + m;
        _Float16* base = Opz + (size_t)(st * 32 + (d >> 5)) * 512
                         + ((d >> 3) & 3) * 128 + (d & 7);
#pragma unroll
        for (int r = 0; r < 4; ++r)
            base[(qd * 4 + r) * 8] = (_Float16)oacc[vt][r];
    }
}

// ---------------------------------------------------------------------------
extern "C" void kernel_launch(void* const* d_in, const int* in_sizes, int n_in,
                              void* d_out, int out_size, void* d_ws, size_t ws_size,
                              hipStream_t stream)
{
    const float* x  = (const float*)d_in[0];
    const float* db = (const float*)d_in[1];
    const float* Wq = (const float*)d_in[2];
    const float* bq = (const float*)d_in[3];
    const float* Wk = (const float*)d_in[4];
    const float* bk = (const float*)d_in[5];
    const float* Wv = (const float*)d_in[6];
    const float* bv = (const float*)d_in[7];
    const float* Wo = (const float*)d_in[8];
    const float* bo = (const float*)d_in[9];
    float* out = (float*)d_out;

    _Float16* ws  = (_Float16*)d_ws;
    _Float16* xh  = ws;               // 2M: packed x (dead after QKV gemm)
    _Float16* wqh = xh  + 2097152;    // 1M each, packed (wq/wk dead after QKV)
    _Float16* wkh = wqh + 1048576;
    _Float16* wvh = wkh + 1048576;
    _Float16* woh = wvh + 1048576;    // packed, used by out-proj
    _Float16* Qb  = woh + 1048576;    // 2M: [h][n][dk], pre-scaled by 0.125
    _Float16* Kb  = Qb  + 2097152;    // 2M: K frag-tiled (KIDX)
    _Float16* Vtb = Kb  + 2097152;    // 2M: V frag-tiled (VIDX)
    _Float16* Oh0 = Vtb + 2097152;    // 2M: attn partial (kv-half 0), PACK
    _Float16* Oh1 = Oh0 + 2097152;    // 2M: attn partial (kv-half 1), PACK

    // bias fp16: prefer a DISJOINT region (fused conversion in cast_pack,
    // before QKV) if ws allows 40 MB; else overlay dead xh/wqh/wkh and use
    // the standalone cvt_bias dispatch after QKV (r6-proven fallback).
    const bool big_ws = ws_size >= (size_t)41943040;  // 20M halves
    _Float16* bh = big_ws ? (Oh1 + 2097152) : ws;

    // fused cast+pack (+ bias convert when big_ws): 5120 vs 3072 blocks
    cast_pack<<<big_ws ? 5120 : 3072, 256, 0, stream>>>(
        x, Wq, Wk, Wv, Wo, db, xh, bh);

    // fused QKV projection: 128x128 tiles, BK=64 -> 384 blocks, 2/CU (64 KB),
    // W-panel re-reads halved, 64x64 wave tile (intensity 2.0)
    tgemm<128, 128, 64, 0><<<dim3(16, 24), 256, 0, stream>>>(
        xh, nullptr, wqh, wkh, wvh, bq, bk, bv, Qb, Kb, Vtb, nullptr);

    if (!big_ws)   // fallback: bias -> fp16 overlaying now-dead xh/wqh/wkh
        cvt_bias<<<4096, 256, 0, stream>>>(db, bh);

    // attention: (head, q-128-tile, kv-half) = 512 blocks, 8 waves each,
    // 2 blocks/CU, fp16 bias (proven 47.6 us configuration)
    attn<<<dim3(NHEAD, NSEQ / 128, 2), 512, 0, stream>>>(Qb, Kb, Vtb, bh, Oh0);

    // output projection with FUSED combine (native fp16 add): 64x64 tiles,
    // BK=64 -> 512 blocks = 2 resident blocks/CU
    tgemm<64, 64, 64, 1><<<dim3(32, 16), 256, 0, stream>>>(
        Oh0, Oh1, woh, nullptr, nullptr, bo, nullptr, nullptr,
        nullptr, nullptr, nullptr, out);
}

// Round 11
// 170.092 us; speedup vs baseline: 1.0070x; 1.0070x over previous
//
#include <hip/hip_runtime.h>
#include <hip/hip_fp16.h>

typedef _Float16 half8 __attribute__((ext_vector_type(8)));
typedef _Float16 half4v __attribute__((ext_vector_type(4)));
typedef float f32x4 __attribute__((ext_vector_type(4)));

#define NSEQ 2048
#define DMOD 1024
#define NHEAD 16
#define DK 64

// async global->LDS, 16B per lane; LDS dest = wave-uniform base + lane*16
#define GLOAD_LDS16(gp, lp) __builtin_amdgcn_global_load_lds(                 \
    (const __attribute__((address_space(1))) void*)(gp),                      \
    (__attribute__((address_space(3))) void*)(lp), 16, 0, 0)

// s_waitcnt imm (gfx9): vmcnt[3:0]=bits[3:0], expcnt=bits[6:4], lgkm=bits[11:8]
#define WAIT_VM(n) (0xF70 | (n))

// ---------------------------------------------------------------------------
// PACKED tile layout for GEMM operands (K=1024):
//   PACK[((st*32 + kc)*64 + ln)*8 + j] = M[st*16 + (ln&15)][kc*32 + (ln>>4)*8 + j]
// One global_load_lds per wave = contiguous 1 KiB burst in fragment order.
// ---------------------------------------------------------------------------

// cast fp32 -> fp16 AND pack into tile order: x (2M) | Wq|Wk|Wv|Wo (1M each).
// Extended (when ws allows): w in [12288,20480) converts distance_bias
// fp32 -> fp16 flat (512 floats per wave-unit), removing the cvt_bias
// dispatch (small streaming kernels pay a ~10us launch/ramp floor).
__global__ __launch_bounds__(256) void cast_pack(
    const float* __restrict__ x, const float* __restrict__ wq,
    const float* __restrict__ wk, const float* __restrict__ wv,
    const float* __restrict__ wo, const float* __restrict__ db,
    _Float16* __restrict__ dst, _Float16* __restrict__ bh)
{
    const int w = blockIdx.x * 4 + (threadIdx.x >> 6);
    const int ln = threadIdx.x & 63, m = ln & 15, qd = ln >> 4;
    if (w >= 12288) {   // bias conversion chunk (flat copy, no repack)
        const int loc = w - 12288;                  // [0, 8192)
        const float* p = db + (size_t)loc * 512 + ln * 8;
        float4 a = *(const float4*)p, b = *(const float4*)(p + 4);
        half8 h;
        h[0] = (_Float16)a.x; h[1] = (_Float16)a.y; h[2] = (_Float16)a.z; h[3] = (_Float16)a.w;
        h[4] = (_Float16)b.x; h[5] = (_Float16)b.y; h[6] = (_Float16)b.z; h[7] = (_Float16)b.w;
        *(half8*)(bh + (size_t)loc * 512 + ln * 8) = h;
        return;
    }
    const float* src; _Float16* d; int loc;
    if (w < 4096) { src = x; d = dst; loc = w; }                // x: 128 st x 32 kc
    else {
        const int w2 = w - 4096, mat = w2 >> 11;                 // W: 64 st x 32 kc
        loc = w2 & 2047;
        src = mat == 0 ? wq : mat == 1 ? wk : mat == 2 ? wv : wo;
        d = dst + 2097152 + mat * 1048576;
    }
    const int st = loc >> 5, kc = loc & 31;
    const float* p = src + (size_t)(st * 16 + m) * 1024 + kc * 32 + qd * 8;
    float4 a = *(const float4*)p, b = *(const float4*)(p + 4);
    half8 h;
    h[0] = (_Float16)a.x; h[1] = (_Float16)a.y; h[2] = (_Float16)a.z; h[3] = (_Float16)a.w;
    h[4] = (_Float16)b.x; h[5] = (_Float16)b.y; h[6] = (_Float16)b.z; h[7] = (_Float16)b.w;
    *(half8*)(d + (size_t)(loc * 64 + ln) * 8) = h;
}

// fallback bias fp32 -> fp16 (only if ws too small for the fused path)
__global__ __launch_bounds__(256) void cvt_bias(
    const float* __restrict__ src, _Float16* __restrict__ dst)
{
    int i = (blockIdx.x * 256 + threadIdx.x) * 4;
    float4 v = *(const float4*)(src + i);
    half4v h;
    h[0] = (_Float16)v.x; h[1] = (_Float16)v.y;
    h[2] = (_Float16)v.z; h[3] = (_Float16)v.w;
    *(half4v*)(dst + i) = h;
}

// ---------------------------------------------------------------------------
// Tiled GEMM, generalized K-step (BK), DOUBLE-buffered, staged ONE STEP
// AHEAD with counted vmcnt + 2 raw barriers per step.  BK=64 halves the
// sync-rendezvous count vs BK=32 (proven r9: -11 us).  PACKED operands.
// C = A @ W^T + bias, K = 1024.  Wave grid 2x2.
// MODE 0: fused QKV epilogue (Q pre-scaled 0.125 at [h][n][dk]; K,V in attn
//         frag-tile order KIDX/VIDX).  BM=64 -> 768 blocks = exactly 3
//         resident blocks/CU (proven r5/r9; the r10 128x128 variant lost
//         its cache win to the 1.5-round tail at 2/CU).
// MODE 1: fp32 out (final projection), A = A1 + A2 summed via native fp16
//         vector add (v_pk_add_f16 - numerically identical to the fp32
//         add+round path, 1/8 the VALU ops).
// ---------------------------------------------------------------------------
template<int BM, int BN, int BK, int MODE>
__global__ __launch_bounds__(256) void tgemm(
    const _Float16* __restrict__ A, const _Float16* __restrict__ A2,
    const _Float16* __restrict__ W0, const _Float16* __restrict__ W1,
    const _Float16* __restrict__ W2,
    const float* __restrict__ b0, const float* __restrict__ b1,
    const float* __restrict__ b2,
    _Float16* __restrict__ oQ, _Float16* __restrict__ oK,
    _Float16* __restrict__ oV, float* __restrict__ oF)
{
    constexpr int MT = BM / 32, NT = BN / 32;
    constexpr int KC = BK / 32;                  // 32-col K-chunks per step
    constexpr int NSTEP = 1024 / BK;
    constexpr int NAc = BM / 64, NBc = BN / 64;  // DMA instr/wave per chunk
    constexpr int SDMA = KC * ((MODE == 1 ? 2 * NAc : NAc) + NBc);
    __shared__ _Float16 sA[2 * BM * BK];
    __shared__ _Float16 sA2[MODE == 1 ? 2 * BM * BK : 1];
    __shared__ _Float16 sB[2 * BN * BK];
    const int tid = threadIdx.x, wv = tid >> 6, ln = tid & 63;
    const int m = ln & 15, qd = ln >> 4;
    const int row0 = blockIdx.x * BM;

    int sel = 0, colbase;
    const _Float16* W; const float* bias;
    if constexpr (MODE == 0) {
        sel = blockIdx.y >> 3;
        colbase = (blockIdx.y & 7) * BN;
        W = sel == 0 ? W0 : sel == 1 ? W1 : W2;
        bias = sel == 0 ? b0 : sel == 1 ? b1 : b2;
    } else {
        colbase = blockIdx.y * BN;
        W = W0; bias = b0;
    }
    const int wr = wv >> 1, wc = wv & 1;

    f32x4 acc[MT][NT];
#pragma unroll
    for (int i = 0; i < MT; ++i)
#pragma unroll
        for (int j = 0; j < NT; ++j) acc[i][j] = (f32x4){0.f, 0.f, 0.f, 0.f};

    auto stage = [&](int s, int b) {
        _Float16* dA = sA + b * (BM * BK);
        _Float16* dB = sB + b * (BN * BK);
#pragma unroll
        for (int c = 0; c < KC; ++c) {
            const int kc = s * KC + c;
#pragma unroll
            for (int ra = 0; ra < NAc; ++ra) {
                const int st = ra * 4 + wv;
                GLOAD_LDS16(A + ((size_t)((row0 >> 4) + st) * 32 + kc) * 512 + ln * 8,
                            dA + (c * (BM / 16) + st) * 512);
                if constexpr (MODE == 1) {
                    _Float16* dA2 = sA2 + b * (BM * BK);
                    GLOAD_LDS16(A2 + ((size_t)((row0 >> 4) + st) * 32 + kc) * 512 + ln * 8,
                                dA2 + (c * (BM / 16) + st) * 512);
                }
            }
#pragma unroll
            for (int rb = 0; rb < NBc; ++rb) {
                const int st = rb * 4 + wv;
                GLOAD_LDS16(W + ((size_t)((colbase >> 4) + st) * 32 + kc) * 512 + ln * 8,
                            dB + (c * (BN / 16) + st) * 512);
            }
        }
    };
    auto step = [&](int b) {
#pragma unroll
        for (int c = 0; c < KC; ++c) {
            const _Float16* cA = sA + b * (BM * BK) + c * (BM * 32);
            const _Float16* cB = sB + b * (BN * BK) + c * (BN * 32);
            half8 af[MT], bf[NT];
#pragma unroll
            for (int i = 0; i < MT; ++i) {
                const int off = ((wr * MT + i) * 64 + ln) * 8;
                if constexpr (MODE == 1) {
                    const _Float16* cA2 = sA2 + b * (BM * BK) + c * (BM * 32);
                    half8 xv = *(const half8*)(cA + off);
                    half8 yv = *(const half8*)(cA2 + off);
                    af[i] = xv + yv;   // v_pk_add_f16: == fp32-add-then-round
                } else {
                    af[i] = *(const half8*)(cA + off);
                }
            }
#pragma unroll
            for (int j = 0; j < NT; ++j)
                bf[j] = *(const half8*)(cB + ((wc * NT + j) * 64 + ln) * 8);
#pragma unroll
            for (int i = 0; i < MT; ++i)
#pragma unroll
                for (int j = 0; j < NT; ++j)
                    acc[i][j] = __builtin_amdgcn_mfma_f32_16x16x32_f16(af[i], bf[j], acc[i][j], 0, 0, 0);
        }
    };

    // K-loop: dbuf, stage 1 step ahead, counted vmcnt, 2 barriers/step.
    stage(0, 0);
#pragma unroll
    for (int s = 0; s < NSTEP; ++s) {
        if (s) __builtin_amdgcn_s_barrier();          // prev step's reads done
        if (s + 1 < NSTEP) {
            stage(s + 1, (s + 1) & 1);
            __builtin_amdgcn_s_waitcnt(WAIT_VM(SDMA));  // step s's loads done
        } else {
            __builtin_amdgcn_s_waitcnt(WAIT_VM(0));     // final: drain all
        }
        __builtin_amdgcn_s_barrier();                 // buf[s&1] visible
        step(s & 1);
    }

#pragma unroll
    for (int j = 0; j < NT; ++j) {
        const int col = colbase + wc * (BN / 2) + j * 16 + m;
        const float bv = bias[col];
#pragma unroll
        for (int i = 0; i < MT; ++i) {
            const int crow0 = row0 + wr * (BM / 2) + i * 16 + qd * 4;
            if constexpr (MODE == 1) {
#pragma unroll
                for (int r = 0; r < 4; ++r)
                    oF[(size_t)(crow0 + r) * DMOD + col] = acc[i][j][r] + bv;
            } else {
                const int h = col >> 6, d = col & 63;
                if (sel == 0) {
#pragma unroll
                    for (int r = 0; r < 4; ++r)
                        oQ[h * (NSEQ * DK) + (crow0 + r) * DK + d] =
                            (_Float16)((acc[i][j][r] + bv) * 0.125f);
                } else if (sel == 1) {
                    // K frag-tile order (KIDX)
#pragma unroll
                    for (int r = 0; r < 4; ++r) {
                        const int n = crow0 + r;
                        oK[(size_t)(((h * 16 + (n >> 7)) * 16
                                     + ((n >> 4) & 7) * 2 + (d >> 5)) * 64
                                    + (n & 15) + 16 * ((d >> 3) & 3)) * 8
                           + (d & 7)] = (_Float16)(acc[i][j][r] + bv);
                    }
                } else {
                    // V frag-tile order (VIDX); 4 consecutive n contiguous
                    half4v hv;
#pragma unroll
                    for (int r = 0; r < 4; ++r) hv[r] = (_Float16)(acc[i][j][r] + bv);
                    const int n0 = crow0;
                    *(half4v*)(oV + (size_t)(((h * 16 + (n0 >> 7)) * 16
                                              + ((n0 >> 5) & 3) * 4 + ((d >> 4) & 3)) * 64
                                             + (d & 15) + 16 * ((n0 >> 3) & 3)) * 8
                               + (n0 & 7)) = hv;
                }
            }
        }
    }
}

// ---------------------------------------------------------------------------
// Attention v12-exact (proven 47.6 us: 8 waves x 16 q, sP round-trip,
// KVBLK=128, 2 __syncthreads per step, fp16 bias).  UNTOUCHED.
// LDS = 16(K) + 16(V) + 32(P) = 64 KB -> 2 blocks/CU, 16 waves/CU.
// ---------------------------------------------------------------------------
__global__ __launch_bounds__(512, 4) void attn(
    const _Float16* __restrict__ Q, const _Float16* __restrict__ Kt,
    const _Float16* __restrict__ Vt, const _Float16* __restrict__ bias_h,
    _Float16* __restrict__ Op)
{
    __shared__ _Float16 sK[8192];
    __shared__ _Float16 sV[8192];
    __shared__ _Float16 sP[16384];  // [8 waves][2048]
    const int tid = threadIdx.x, wv = tid >> 6, ln = tid & 63;
    const int m = ln & 15, qd = ln >> 4;
    const int h = blockIdx.x;
    const int q0 = blockIdx.y * 128 + wv * 16;    // this wave's 16 q-rows
    const int kvb = blockIdx.z * 8;               // first 128-key step of half
    const _Float16* Qh = Q + h * (NSEQ * DK);
    const _Float16* Kh = Kt + h * (NSEQ * DK) + kvb * 8192;  // [step][f][ln][8]
    const _Float16* Vh = Vt + h * (NSEQ * DK) + kvb * 8192;
    const _Float16* brow = bias_h + (size_t)(q0 + m) * NSEQ + kvb * 128;

    // Q B-fragments (pre-scaled by 1/8), 2 dk-halves
    half8 qf[2];
    qf[0] = *(const half8*)(Qh + (q0 + m) * DK + qd * 8);
    qf[1] = *(const half8*)(Qh + (q0 + m) * DK + 32 + qd * 8);

    f32x4 oacc[4], oU[4];
#pragma unroll
    for (int v = 0; v < 4; ++v) {
        oacc[v] = (f32x4){0.f, 0.f, 0.f, 0.f};
        oU[v]   = (f32x4){0.f, 0.f, 0.f, 0.f};
    }
    float bsum = 0.f;

    for (int ls = 0; ls < 8; ++ls) {
        if (ls) __syncthreads();   // previous step's LDS reads complete
        // --- stage K,V: 16 frags each, 2 per wave ---
        GLOAD_LDS16(Kh + ls * 8192 + wv * 512 + ln * 8, sK + wv * 512);
        GLOAD_LDS16(Kh + ls * 8192 + (wv + 8) * 512 + ln * 8, sK + (wv + 8) * 512);
        GLOAD_LDS16(Vh + ls * 8192 + wv * 512 + ln * 8, sV + wv * 512);
        GLOAD_LDS16(Vh + ls * 8192 + (wv + 8) * 512 + ln * 8, sV + (wv + 8) * 512);
        // --- bias regs (fp16, 8B/lane); drain together with DMA ---
        half4v bcur[8];
#pragma unroll
        for (int t = 0; t < 8; ++t)
            bcur[t] = *(const half4v*)(brow + ls * 128 + t * 16 + qd * 4);
        __syncthreads();           // staging visible

        // --- S^T phase ---
#pragma unroll
        for (int t = 0; t < 8; ++t) {
            half8 kf0 = *(const half8*)(sK + ((t * 2 + 0) * 64 + ln) * 8);
            half8 kf1 = *(const half8*)(sK + ((t * 2 + 1) * 64 + ln) * 8);
            f32x4 s = {0.f, 0.f, 0.f, 0.f};
            s = __builtin_amdgcn_mfma_f32_16x16x32_f16(kf0, qf[0], s, 0, 0, 0);
            s = __builtin_amdgcn_mfma_f32_16x16x32_f16(kf1, qf[1], s, 0, 0, 0);
            float p0 = __expf(s[0] - (float)bcur[t][0]);
            float p1 = __expf(s[1] - (float)bcur[t][1]);
            float p2 = __expf(s[2] - (float)bcur[t][2]);
            float p3 = __expf(s[3] - (float)bcur[t][3]);
            bsum += (p0 + p1) + (p2 + p3);
            half4v ph;
            ph[0] = (_Float16)p0; ph[1] = (_Float16)p1;
            ph[2] = (_Float16)p2; ph[3] = (_Float16)p3;
            // (q=m, key=t*16+qd*4+r) -> A-frag slot (verified transform)
            *(half4v*)(sP + wv * 2048 + (t >> 1) * 512
                       + (((t & 1) * 2 + (qd >> 1)) * 16 + m) * 8
                       + (qd & 1) * 4) = ph;
        }

        // --- PV phase ---
#pragma unroll
        for (int kk = 0; kk < 4; ++kk) {
            half8 pa = *(const half8*)(sP + wv * 2048 + kk * 512 + ln * 8);
#pragma unroll
            for (int vt = 0; vt < 4; ++vt) {
                half8 vb = *(const half8*)(sV + ((kk * 4 + vt) * 64 + ln) * 8);
                oU[vt] = __builtin_amdgcn_mfma_f32_16x16x32_f16(pa, vb, oU[vt], 0, 0, 0);
            }
        }

        // --- end of a 256-key softmax block: fold in 1/(8*sum) ---
        if (ls & 1) {
            float s2 = bsum;
            s2 += __shfl_xor(s2, 16, 64);
            s2 += __shfl_xor(s2, 32, 64);
            float inv = 1.0f / (8.0f * s2);
            float iv[4];
#pragma unroll
            for (int r = 0; r < 4; ++r) iv[r] = __shfl(inv, qd * 4 + r, 64);
#pragma unroll
            for (int vt = 0; vt < 4; ++vt) {
#pragma unroll
                for (int r = 0; r < 4; ++r) oacc[vt][r] += iv[r] * oU[vt][r];
                oU[vt] = (f32x4){0.f, 0.f, 0.f, 0.f};
            }
            bsum = 0.f;
        }
    }

    // ---- store partial O in PACK layout (out-proj A-operand) ----
    // n = q0 + qd*4 + r ; d = h*64 + vt*16 + m
    _Float16* Opz = Op + (size_t)blockIdx.z * 2097152;
    const int st = blockIdx.y * 8 + wv;
#pragma unroll
    for (int vt = 0; vt < 4; ++vt) {
        const int d = h * 64 + vt * 16 + m;
        _Float16* base = Opz + (size_t)(st * 32 + (d >> 5)) * 512
                         + ((d >> 3) & 3) * 128 + (d & 7);
#pragma unroll
        for (int r = 0; r < 4; ++r)
            base[(qd * 4 + r) * 8] = (_Float16)oacc[vt][r];
    }
}

// ---------------------------------------------------------------------------
extern "C" void kernel_launch(void* const* d_in, const int* in_sizes, int n_in,
                              void* d_out, int out_size, void* d_ws, size_t ws_size,
                              hipStream_t stream)
{
    const float* x  = (const float*)d_in[0];
    const float* db = (const float*)d_in[1];
    const float* Wq = (const float*)d_in[2];
    const float* bq = (const float*)d_in[3];
    const float* Wk = (const float*)d_in[4];
    const float* bk = (const float*)d_in[5];
    const float* Wv = (const float*)d_in[6];
    const float* bv = (const float*)d_in[7];
    const float* Wo = (const float*)d_in[8];
    const float* bo = (const float*)d_in[9];
    float* out = (float*)d_out;

    _Float16* ws  = (_Float16*)d_ws;
    _Float16* xh  = ws;               // 2M: packed x (dead after QKV gemm)
    _Float16* wqh = xh  + 2097152;    // 1M each, packed (wq/wk dead after QKV)
    _Float16* wkh = wqh + 1048576;
    _Float16* wvh = wkh + 1048576;
    _Float16* woh = wvh + 1048576;    // packed, used by out-proj
    _Float16* Qb  = woh + 1048576;    // 2M: [h][n][dk], pre-scaled by 0.125
    _Float16* Kb  = Qb  + 2097152;    // 2M: K frag-tiled (KIDX)
    _Float16* Vtb = Kb  + 2097152;    // 2M: V frag-tiled (VIDX)
    _Float16* Oh0 = Vtb + 2097152;    // 2M: attn partial (kv-half 0), PACK
    _Float16* Oh1 = Oh0 + 2097152;    // 2M: attn partial (kv-half 1), PACK

    // bias fp16: prefer a DISJOINT region (fused conversion in cast_pack,
    // before QKV) if ws allows 40 MB; else overlay dead xh/wqh/wkh and use
    // the standalone cvt_bias dispatch after QKV (r6-proven fallback).
    const bool big_ws = ws_size >= (size_t)41943040;  // 20M halves
    _Float16* bh = big_ws ? (Oh1 + 2097152) : ws;

    // fused cast+pack (+ bias convert when big_ws): 5120 vs 3072 blocks
    cast_pack<<<big_ws ? 5120 : 3072, 256, 0, stream>>>(
        x, Wq, Wk, Wv, Wo, db, xh, bh);

    // fused QKV projection: 64x128 tiles, BK=64 -> 768 blocks = exactly 3/CU
    // (proven r9 configuration; r10's 128x128 lost its cache win to the tail)
    tgemm<64, 128, 64, 0><<<dim3(32, 24), 256, 0, stream>>>(
        xh, nullptr, wqh, wkh, wvh, bq, bk, bv, Qb, Kb, Vtb, nullptr);

    if (!big_ws)   // fallback: bias -> fp16 overlaying now-dead xh/wqh/wkh
        cvt_bias<<<4096, 256, 0, stream>>>(db, bh);

    // attention: (head, q-128-tile, kv-half) = 512 blocks, 8 waves each,
    // 2 blocks/CU, fp16 bias (proven 47.6 us configuration)
    attn<<<dim3(NHEAD, NSEQ / 128, 2), 512, 0, stream>>>(Qb, Kb, Vtb, bh, Oh0);

    // output projection with FUSED combine (native fp16 add): 64x64 tiles,
    // BK=64 -> 512 blocks = 2 resident blocks/CU
    tgemm<64, 64, 64, 1><<<dim3(32, 16), 256, 0, stream>>>(
        Oh0, Oh1, woh, nullptr, nullptr, bo, nullptr, nullptr,
        nullptr, nullptr, nullptr, out);
}

// Round 12
// 161.855 us; speedup vs baseline: 1.0582x; 1.0509x over previous
//
#include <hip/hip_runtime.h>
#include <hip/hip_fp16.h>

typedef _Float16 half8 __attribute__((ext_vector_type(8)));
typedef _Float16 half4v __attribute__((ext_vector_type(4)));
typedef float f32x4 __attribute__((ext_vector_type(4)));

#define NSEQ 2048
#define DMOD 1024
#define NHEAD 16
#define DK 64

// async global->LDS, 16B per lane; LDS dest = wave-uniform base + lane*16
#define GLOAD_LDS16(gp, lp) __builtin_amdgcn_global_load_lds(                 \
    (const __attribute__((address_space(1))) void*)(gp),                      \
    (__attribute__((address_space(3))) void*)(lp), 16, 0, 0)

// s_waitcnt imm (gfx9): vmcnt[3:0]=bits[3:0], expcnt=bits[6:4], lgkm=bits[11:8]
#define WAIT_VM(n) (0xF70 | (n))

// ---------------------------------------------------------------------------
// PACKED tile layout for GEMM operands (K=1024):
//   PACK[((st*32 + kc)*64 + ln)*8 + j] = M[st*16 + (ln&15)][kc*32 + (ln>>4)*8 + j]
// BIDX bias layout (fp16), built at conversion time so attn's per-(step,t)
// bias read is ONE contiguous 512B wave-load (was 16 scattered rows x 32B):
//   BIDX[(((ks*128 + q0g)*8 + t)*64 + ln)*4 + j]
//     = bias[q0g*16 + (ln&15)][ks*128 + t*16 + (ln>>4)*4 + j]
//   ks = global 128-key step [0,16), q0g = q-row group [0,128).
// ---------------------------------------------------------------------------

// cast fp32 -> fp16 AND pack into tile order: x (2M) | Wq|Wk|Wv|Wo (1M each).
// w in [12288,20480): convert distance_bias fp32 -> fp16 into BIDX layout.
__global__ __launch_bounds__(256) void cast_pack(
    const float* __restrict__ x, const float* __restrict__ wq,
    const float* __restrict__ wk, const float* __restrict__ wv,
    const float* __restrict__ wo, const float* __restrict__ db,
    _Float16* __restrict__ dst, _Float16* __restrict__ bh)
{
    const int w = blockIdx.x * 4 + (threadIdx.x >> 6);
    const int ln = threadIdx.x & 63, m = ln & 15, qd = ln >> 4;
    if (w >= 12288) {   // bias conversion chunk -> BIDX layout
        const int loc = w - 12288;                  // [0, 8192)
        const int ks = loc >> 9;                    // [0,16)
        const int rem = loc & 511;
        const int q0g = rem >> 2;                   // [0,128)
        const int t2 = rem & 3;                     // 2 t-values per unit
#pragma unroll
        for (int tt = 0; tt < 2; ++tt) {
            const int t = t2 * 2 + tt;
            const float* p = db + (size_t)(q0g * 16 + m) * 2048
                             + ks * 128 + t * 16 + qd * 4;
            float4 a = *(const float4*)p;
            half4v h;
            h[0] = (_Float16)a.x; h[1] = (_Float16)a.y;
            h[2] = (_Float16)a.z; h[3] = (_Float16)a.w;
            *(half4v*)(bh + ((((size_t)ks * 128 + q0g) * 8 + t) * 64 + ln) * 4) = h;
        }
        return;
    }
    const float* src; _Float16* d; int loc;
    if (w < 4096) { src = x; d = dst; loc = w; }                // x: 128 st x 32 kc
    else {
        const int w2 = w - 4096, mat = w2 >> 11;                 // W: 64 st x 32 kc
        loc = w2 & 2047;
        src = mat == 0 ? wq : mat == 1 ? wk : mat == 2 ? wv : wo;
        d = dst + 2097152 + mat * 1048576;
    }
    const int st = loc >> 5, kc = loc & 31;
    const float* p = src + (size_t)(st * 16 + m) * 1024 + kc * 32 + qd * 8;
    float4 a = *(const float4*)p, b = *(const float4*)(p + 4);
    half8 h;
    h[0] = (_Float16)a.x; h[1] = (_Float16)a.y; h[2] = (_Float16)a.z; h[3] = (_Float16)a.w;
    h[4] = (_Float16)b.x; h[5] = (_Float16)b.y; h[6] = (_Float16)b.z; h[7] = (_Float16)b.w;
    *(half8*)(d + (size_t)(loc * 64 + ln) * 8) = h;
}

// fallback bias fp32 -> fp16 BIDX (only if ws too small for the fused path)
__global__ __launch_bounds__(256) void cvt_bias(
    const float* __restrict__ db, _Float16* __restrict__ bh)
{
    const int w = blockIdx.x * 4 + (threadIdx.x >> 6);   // [0, 8192)
    const int ln = threadIdx.x & 63, m = ln & 15, qd = ln >> 4;
    const int ks = w >> 9;
    const int rem = w & 511;
    const int q0g = rem >> 2;
    const int t2 = rem & 3;
#pragma unroll
    for (int tt = 0; tt < 2; ++tt) {
        const int t = t2 * 2 + tt;
        const float* p = db + (size_t)(q0g * 16 + m) * 2048
                         + ks * 128 + t * 16 + qd * 4;
        float4 a = *(const float4*)p;
        half4v h;
        h[0] = (_Float16)a.x; h[1] = (_Float16)a.y;
        h[2] = (_Float16)a.z; h[3] = (_Float16)a.w;
        *(half4v*)(bh + ((((size_t)ks * 128 + q0g) * 8 + t) * 64 + ln) * 4) = h;
    }
}

// ---------------------------------------------------------------------------
// Tiled GEMM, generalized K-step (BK), DOUBLE-buffered, staged ONE STEP
// AHEAD with counted vmcnt + 2 raw barriers per step.  BK=64 halves the
// sync-rendezvous count vs BK=32 (proven r9: -11 us).  PACKED operands.
// C = A @ W^T + bias, K = 1024.  Wave grid 2x2.
// MODE 0: fused QKV epilogue (Q pre-scaled 0.125 at [h][n][dk]; K,V in attn
//         frag-tile order KIDX/VIDX).  BM=64 -> 768 blocks = exactly 3/CU.
// MODE 1: fp32 out (final projection), A = A1 + A2 via v_pk_add_f16.
// ---------------------------------------------------------------------------
template<int BM, int BN, int BK, int MODE>
__global__ __launch_bounds__(256) void tgemm(
    const _Float16* __restrict__ A, const _Float16* __restrict__ A2,
    const _Float16* __restrict__ W0, const _Float16* __restrict__ W1,
    const _Float16* __restrict__ W2,
    const float* __restrict__ b0, const float* __restrict__ b1,
    const float* __restrict__ b2,
    _Float16* __restrict__ oQ, _Float16* __restrict__ oK,
    _Float16* __restrict__ oV, float* __restrict__ oF)
{
    constexpr int MT = BM / 32, NT = BN / 32;
    constexpr int KC = BK / 32;                  // 32-col K-chunks per step
    constexpr int NSTEP = 1024 / BK;
    constexpr int NAc = BM / 64, NBc = BN / 64;  // DMA instr/wave per chunk
    constexpr int SDMA = KC * ((MODE == 1 ? 2 * NAc : NAc) + NBc);
    __shared__ _Float16 sA[2 * BM * BK];
    __shared__ _Float16 sA2[MODE == 1 ? 2 * BM * BK : 1];
    __shared__ _Float16 sB[2 * BN * BK];
    const int tid = threadIdx.x, wv = tid >> 6, ln = tid & 63;
    const int m = ln & 15, qd = ln >> 4;
    const int row0 = blockIdx.x * BM;

    int sel = 0, colbase;
    const _Float16* W; const float* bias;
    if constexpr (MODE == 0) {
        sel = blockIdx.y >> 3;
        colbase = (blockIdx.y & 7) * BN;
        W = sel == 0 ? W0 : sel == 1 ? W1 : W2;
        bias = sel == 0 ? b0 : sel == 1 ? b1 : b2;
    } else {
        colbase = blockIdx.y * BN;
        W = W0; bias = b0;
    }
    const int wr = wv >> 1, wc = wv & 1;

    f32x4 acc[MT][NT];
#pragma unroll
    for (int i = 0; i < MT; ++i)
#pragma unroll
        for (int j = 0; j < NT; ++j) acc[i][j] = (f32x4){0.f, 0.f, 0.f, 0.f};

    auto stage = [&](int s, int b) {
        _Float16* dA = sA + b * (BM * BK);
        _Float16* dB = sB + b * (BN * BK);
#pragma unroll
        for (int c = 0; c < KC; ++c) {
            const int kc = s * KC + c;
#pragma unroll
            for (int ra = 0; ra < NAc; ++ra) {
                const int st = ra * 4 + wv;
                GLOAD_LDS16(A + ((size_t)((row0 >> 4) + st) * 32 + kc) * 512 + ln * 8,
                            dA + (c * (BM / 16) + st) * 512);
                if constexpr (MODE == 1) {
                    _Float16* dA2 = sA2 + b * (BM * BK);
                    GLOAD_LDS16(A2 + ((size_t)((row0 >> 4) + st) * 32 + kc) * 512 + ln * 8,
                                dA2 + (c * (BM / 16) + st) * 512);
                }
            }
#pragma unroll
            for (int rb = 0; rb < NBc; ++rb) {
                const int st = rb * 4 + wv;
                GLOAD_LDS16(W + ((size_t)((colbase >> 4) + st) * 32 + kc) * 512 + ln * 8,
                            dB + (c * (BN / 16) + st) * 512);
            }
        }
    };
    auto step = [&](int b) {
#pragma unroll
        for (int c = 0; c < KC; ++c) {
            const _Float16* cA = sA + b * (BM * BK) + c * (BM * 32);
            const _Float16* cB = sB + b * (BN * BK) + c * (BN * 32);
            half8 af[MT], bf[NT];
#pragma unroll
            for (int i = 0; i < MT; ++i) {
                const int off = ((wr * MT + i) * 64 + ln) * 8;
                if constexpr (MODE == 1) {
                    const _Float16* cA2 = sA2 + b * (BM * BK) + c * (BM * 32);
                    half8 xv = *(const half8*)(cA + off);
                    half8 yv = *(const half8*)(cA2 + off);
                    af[i] = xv + yv;   // v_pk_add_f16: == fp32-add-then-round
                } else {
                    af[i] = *(const half8*)(cA + off);
                }
            }
#pragma unroll
            for (int j = 0; j < NT; ++j)
                bf[j] = *(const half8*)(cB + ((wc * NT + j) * 64 + ln) * 8);
#pragma unroll
            for (int i = 0; i < MT; ++i)
#pragma unroll
                for (int j = 0; j < NT; ++j)
                    acc[i][j] = __builtin_amdgcn_mfma_f32_16x16x32_f16(af[i], bf[j], acc[i][j], 0, 0, 0);
        }
    };

    // K-loop: dbuf, stage 1 step ahead, counted vmcnt, 2 barriers/step.
    stage(0, 0);
#pragma unroll
    for (int s = 0; s < NSTEP; ++s) {
        if (s) __builtin_amdgcn_s_barrier();          // prev step's reads done
        if (s + 1 < NSTEP) {
            stage(s + 1, (s + 1) & 1);
            __builtin_amdgcn_s_waitcnt(WAIT_VM(SDMA));  // step s's loads done
        } else {
            __builtin_amdgcn_s_waitcnt(WAIT_VM(0));     // final: drain all
        }
        __builtin_amdgcn_s_barrier();                 // buf[s&1] visible
        step(s & 1);
    }

#pragma unroll
    for (int j = 0; j < NT; ++j) {
        const int col = colbase + wc * (BN / 2) + j * 16 + m;
        const float bv = bias[col];
#pragma unroll
        for (int i = 0; i < MT; ++i) {
            const int crow0 = row0 + wr * (BM / 2) + i * 16 + qd * 4;
            if constexpr (MODE == 1) {
#pragma unroll
                for (int r = 0; r < 4; ++r)
                    oF[(size_t)(crow0 + r) * DMOD + col] = acc[i][j][r] + bv;
            } else {
                const int h = col >> 6, d = col & 63;
                if (sel == 0) {
#pragma unroll
                    for (int r = 0; r < 4; ++r)
                        oQ[h * (NSEQ * DK) + (crow0 + r) * DK + d] =
                            (_Float16)((acc[i][j][r] + bv) * 0.125f);
                } else if (sel == 1) {
                    // K frag-tile order (KIDX)
#pragma unroll
                    for (int r = 0; r < 4; ++r) {
                        const int n = crow0 + r;
                        oK[(size_t)(((h * 16 + (n >> 7)) * 16
                                     + ((n >> 4) & 7) * 2 + (d >> 5)) * 64
                                    + (n & 15) + 16 * ((d >> 3) & 3)) * 8
                           + (d & 7)] = (_Float16)(acc[i][j][r] + bv);
                    }
                } else {
                    // V frag-tile order (VIDX); 4 consecutive n contiguous
                    half4v hv;
#pragma unroll
                    for (int r = 0; r < 4; ++r) hv[r] = (_Float16)(acc[i][j][r] + bv);
                    const int n0 = crow0;
                    *(half4v*)(oV + (size_t)(((h * 16 + (n0 >> 7)) * 16
                                              + ((n0 >> 5) & 3) * 4 + ((d >> 4) & 3)) * 64
                                             + (d & 15) + 16 * ((n0 >> 3) & 3)) * 8
                               + (n0 & 7)) = hv;
                }
            }
        }
    }
}

// ---------------------------------------------------------------------------
// Attention v18 = v12 structure (proven 47.6 us: 8 waves x 16 q, sP
// round-trip, KVBLK=128, 2 __syncthreads per step) with ONE change: bias
// read from the BIDX layout -> each (step,t) bias load is one contiguous
// 512B wave-load (same pattern as K/V frags), replacing 16-row scatter.
// A wave's whole step = one 4 KB block; a block's step = 32 KB contiguous.
// LDS = 16(K) + 16(V) + 32(P) = 64 KB -> 2 blocks/CU, 16 waves/CU.
// ---------------------------------------------------------------------------
__global__ __launch_bounds__(512, 4) void attn(
    const _Float16* __restrict__ Q, const _Float16* __restrict__ Kt,
    const _Float16* __restrict__ Vt, const _Float16* __restrict__ bias_h,
    _Float16* __restrict__ Op)
{
    __shared__ _Float16 sK[8192];
    __shared__ _Float16 sV[8192];
    __shared__ _Float16 sP[16384];  // [8 waves][2048]
    const int tid = threadIdx.x, wv = tid >> 6, ln = tid & 63;
    const int m = ln & 15, qd = ln >> 4;
    const int h = blockIdx.x;
    const int q0 = blockIdx.y * 128 + wv * 16;    // this wave's 16 q-rows
    const int q0g = blockIdx.y * 8 + wv;          // q-row group [0,128)
    const int kvb = blockIdx.z * 8;               // first 128-key step of half
    const _Float16* Qh = Q + h * (NSEQ * DK);
    const _Float16* Kh = Kt + h * (NSEQ * DK) + kvb * 8192;  // [step][f][ln][8]
    const _Float16* Vh = Vt + h * (NSEQ * DK) + kvb * 8192;
    // BIDX: bias frag for (ks=kvb+ls, q0g, t) at ((ks*128+q0g)*8+t)*256 + ln*4
    const _Float16* bbase = bias_h + ((size_t)kvb * 128 + q0g) * 2048 + ln * 4;

    // Q B-fragments (pre-scaled by 1/8), 2 dk-halves
    half8 qf[2];
    qf[0] = *(const half8*)(Qh + (q0 + m) * DK + qd * 8);
    qf[1] = *(const half8*)(Qh + (q0 + m) * DK + 32 + qd * 8);

    f32x4 oacc[4], oU[4];
#pragma unroll
    for (int v = 0; v < 4; ++v) {
        oacc[v] = (f32x4){0.f, 0.f, 0.f, 0.f};
        oU[v]   = (f32x4){0.f, 0.f, 0.f, 0.f};
    }
    float bsum = 0.f;

    for (int ls = 0; ls < 8; ++ls) {
        if (ls) __syncthreads();   // previous step's LDS reads complete
        // --- stage K,V: 16 frags each, 2 per wave ---
        GLOAD_LDS16(Kh + ls * 8192 + wv * 512 + ln * 8, sK + wv * 512);
        GLOAD_LDS16(Kh + ls * 8192 + (wv + 8) * 512 + ln * 8, sK + (wv + 8) * 512);
        GLOAD_LDS16(Vh + ls * 8192 + wv * 512 + ln * 8, sV + wv * 512);
        GLOAD_LDS16(Vh + ls * 8192 + (wv + 8) * 512 + ln * 8, sV + (wv + 8) * 512);
        // --- bias regs (fp16, one contiguous 512B wave-load per t) ---
        half4v bcur[8];
#pragma unroll
        for (int t = 0; t < 8; ++t)
            bcur[t] = *(const half4v*)(bbase + (size_t)ls * 262144 + t * 256);
        __syncthreads();           // staging visible

        // --- S^T phase ---
#pragma unroll
        for (int t = 0; t < 8; ++t) {
            half8 kf0 = *(const half8*)(sK + ((t * 2 + 0) * 64 + ln) * 8);
            half8 kf1 = *(const half8*)(sK + ((t * 2 + 1) * 64 + ln) * 8);
            f32x4 s = {0.f, 0.f, 0.f, 0.f};
            s = __builtin_amdgcn_mfma_f32_16x16x32_f16(kf0, qf[0], s, 0, 0, 0);
            s = __builtin_amdgcn_mfma_f32_16x16x32_f16(kf1, qf[1], s, 0, 0, 0);
            float p0 = __expf(s[0] - (float)bcur[t][0]);
            float p1 = __expf(s[1] - (float)bcur[t][1]);
            float p2 = __expf(s[2] - (float)bcur[t][2]);
            float p3 = __expf(s[3] - (float)bcur[t][3]);
            bsum += (p0 + p1) + (p2 + p3);
            half4v ph;
            ph[0] = (_Float16)p0; ph[1] = (_Float16)p1;
            ph[2] = (_Float16)p2; ph[3] = (_Float16)p3;
            // (q=m, key=t*16+qd*4+r) -> A-frag slot (verified transform)
            *(half4v*)(sP + wv * 2048 + (t >> 1) * 512
                       + (((t & 1) * 2 + (qd >> 1)) * 16 + m) * 8
                       + (qd & 1) * 4) = ph;
        }

        // --- PV phase ---
#pragma unroll
        for (int kk = 0; kk < 4; ++kk) {
            half8 pa = *(const half8*)(sP + wv * 2048 + kk * 512 + ln * 8);
#pragma unroll
            for (int vt = 0; vt < 4; ++vt) {
                half8 vb = *(const half8*)(sV + ((kk * 4 + vt) * 64 + ln) * 8);
                oU[vt] = __builtin_amdgcn_mfma_f32_16x16x32_f16(pa, vb, oU[vt], 0, 0, 0);
            }
        }

        // --- end of a 256-key softmax block: fold in 1/(8*sum) ---
        if (ls & 1) {
            float s2 = bsum;
            s2 += __shfl_xor(s2, 16, 64);
            s2 += __shfl_xor(s2, 32, 64);
            float inv = 1.0f / (8.0f * s2);
            float iv[4];
#pragma unroll
            for (int r = 0; r < 4; ++r) iv[r] = __shfl(inv, qd * 4 + r, 64);
#pragma unroll
            for (int vt = 0; vt < 4; ++vt) {
#pragma unroll
                for (int r = 0; r < 4; ++r) oacc[vt][r] += iv[r] * oU[vt][r];
                oU[vt] = (f32x4){0.f, 0.f, 0.f, 0.f};
            }
            bsum = 0.f;
        }
    }

    // ---- store partial O in PACK layout (out-proj A-operand) ----
    // n = q0 + qd*4 + r ; d = h*64 + vt*16 + m
    _Float16* Opz = Op + (size_t)blockIdx.z * 2097152;
    const int st = q0g;
#pragma unroll
    for (int vt = 0; vt < 4; ++vt) {
        const int d = h * 64 + vt * 16 + m;
        _Float16* base = Opz + (size_t)(st * 32 + (d >> 5)) * 512
                         + ((d >> 3) & 3) * 128 + (d & 7);
#pragma unroll
        for (int r = 0; r < 4; ++r)
            base[(qd * 4 + r) * 8] = (_Float16)oacc[vt][r];
    }
}

// ---------------------------------------------------------------------------
extern "C" void kernel_launch(void* const* d_in, const int* in_sizes, int n_in,
                              void* d_out, int out_size, void* d_ws, size_t ws_size,
                              hipStream_t stream)
{
    const float* x  = (const float*)d_in[0];
    const float* db = (const float*)d_in[1];
    const float* Wq = (const float*)d_in[2];
    const float* bq = (const float*)d_in[3];
    const float* Wk = (const float*)d_in[4];
    const float* bk = (const float*)d_in[5];
    const float* Wv = (const float*)d_in[6];
    const float* bv = (const float*)d_in[7];
    const float* Wo = (const float*)d_in[8];
    const float* bo = (const float*)d_in[9];
    float* out = (float*)d_out;

    _Float16* ws  = (_Float16*)d_ws;
    _Float16* xh  = ws;               // 2M: packed x (dead after QKV gemm)
    _Float16* wqh = xh  + 2097152;    // 1M each, packed (wq/wk dead after QKV)
    _Float16* wkh = wqh + 1048576;
    _Float16* wvh = wkh + 1048576;
    _Float16* woh = wvh + 1048576;    // packed, used by out-proj
    _Float16* Qb  = woh + 1048576;    // 2M: [h][n][dk], pre-scaled by 0.125
    _Float16* Kb  = Qb  + 2097152;    // 2M: K frag-tiled (KIDX)
    _Float16* Vtb = Kb  + 2097152;    // 2M: V frag-tiled (VIDX)
    _Float16* Oh0 = Vtb + 2097152;    // 2M: attn partial (kv-half 0), PACK
    _Float16* Oh1 = Oh0 + 2097152;    // 2M: attn partial (kv-half 1), PACK

    // bias fp16 (BIDX layout): prefer a DISJOINT region (fused conversion in
    // cast_pack, before QKV) if ws allows 40 MB; else overlay dead
    // xh/wqh/wkh and use the standalone cvt_bias dispatch after QKV.
    const bool big_ws = ws_size >= (size_t)41943040;  // 20M halves
    _Float16* bh = big_ws ? (Oh1 + 2097152) : ws;

    // fused cast+pack (+ bias convert when big_ws): 5120 vs 3072 blocks
    cast_pack<<<big_ws ? 5120 : 3072, 256, 0, stream>>>(
        x, Wq, Wk, Wv, Wo, db, xh, bh);

    // fused QKV projection: 64x128 tiles, BK=64 -> 768 blocks = exactly 3/CU
    tgemm<64, 128, 64, 0><<<dim3(32, 24), 256, 0, stream>>>(
        xh, nullptr, wqh, wkh, wvh, bq, bk, bv, Qb, Kb, Vtb, nullptr);

    if (!big_ws)   // fallback: bias -> fp16 BIDX overlaying dead xh/wqh/wkh
        cvt_bias<<<2048, 256, 0, stream>>>(db, bh);

    // attention: (head, q-128-tile, kv-half) = 512 blocks, 8 waves each,
    // 2 blocks/CU, BIDX coalesced bias
    attn<<<dim3(NHEAD, NSEQ / 128, 2), 512, 0, stream>>>(Qb, Kb, Vtb, bh, Oh0);

    // output projection with FUSED combine (native fp16 add): 64x64 tiles,
    // BK=64 -> 512 blocks = 2 resident blocks/CU
    tgemm<64, 64, 64, 1><<<dim3(32, 16), 256, 0, stream>>>(
        Oh0, Oh1, woh, nullptr, nullptr, bo, nullptr, nullptr,
        nullptr, nullptr, nullptr, out);
}